// Round 1
// baseline (994.626 us; speedup 1.0000x reference)
//
#include <hip/hip_runtime.h>

#define S  2048
#define DH 64
#define NB 32

typedef float f32x4  __attribute__((ext_vector_type(4)));
typedef short bf16x8 __attribute__((ext_vector_type(8)));

__device__ __forceinline__ short f2bf(float f) {
  union { float f; unsigned u; } v; v.f = f;
  unsigned r = v.u + 0x7FFFu + ((v.u >> 16) & 1u);  // RNE
  return (short)(r >> 16);
}

__device__ __forceinline__ float bf2f(short s) {
  union { unsigned u; float f; } v;
  v.u = ((unsigned)(unsigned short)s) << 16;
  return v.f;
}

// load 8 consecutive floats, convert to bf16x8 (A/B fragment half)
__device__ __forceinline__ bf16x8 load8_bf16(const float* p) {
  const float4* p4 = (const float4*)p;
  float4 a = p4[0], b = p4[1];
  bf16x8 o;
  o[0] = f2bf(a.x); o[1] = f2bf(a.y); o[2] = f2bf(a.z); o[3] = f2bf(a.w);
  o[4] = f2bf(b.x); o[5] = f2bf(b.y); o[6] = f2bf(b.z); o[7] = f2bf(b.w);
  return o;
}

// Fragment layouts (verified, m89/m91): 16x16x32 bf16
//   A: lane holds A[m = lane&15][k = (lane>>4)*8 + j], j=0..7
//   B: lane holds B[k = (lane>>4)*8 + j][n = lane&15]
//   C/D: reg r holds D[row = (lane>>4)*4 + r][col = lane&15]
__launch_bounds__(256, 4)
__global__ void attn_kernel(const float* __restrict__ Q, const float* __restrict__ K,
                            const float* __restrict__ V, float* __restrict__ Out,
                            float* __restrict__ Attn) {
  // ptile: per-wave P round-trip (C-layout -> A-layout); also the staging
  // buffer for the coalesced attn store. +8 pad keeps b128 reads 2-way (free).
  // obuf ALIASES ptile (obuf only live after the c-loop; barrier separates).
  // LDS total = 36864 + 1024 = 37888 B -> 4 blocks/CU (was 55296 -> 2 blocks/CU).
  __shared__ __align__(16) char smem[4 * 64 * 72 * sizeof(short)];  // 36864 B
  short (*ptile)[64][72] = (short (*)[64][72])smem;
  float (*obuf)[68]      = (float (*)[68])smem;   // 64x68 floats = 17408 B, fits
  __shared__ float rs[64][4];                     // 1024 B per-wave row sums

  const int b     = blockIdx.x >> 5;
  const int qbase = (blockIdx.x & 31) * 64;
  const int tid   = threadIdx.x;
  const int w     = tid >> 6;
  const int lane  = tid & 63;
  const int quad  = lane >> 4;
  const int col   = lane & 15;

  const float* Qb = Q + (size_t)b * S * DH;
  const float* Kb = K + (size_t)b * S * DH;
  const float* Vb = V + (size_t)b * S * DH;
  float* Ab = Attn + (size_t)b * S * S;

  // Q A-fragments: 4 row-tiles x 2 k-steps, resident in VGPRs for the whole block
  bf16x8 qa[4][2];
#pragma unroll
  for (int rt = 0; rt < 4; ++rt) {
    int row = qbase + rt * 16 + col;
#pragma unroll
    for (int kc = 0; kc < 2; ++kc)
      qa[rt][kc] = load8_bf16(Qb + row * DH + kc * 32 + quad * 8);
  }

  // ================= phase 1: per-row sum of exp(score) =================
  float l[4][4];
#pragma unroll
  for (int i = 0; i < 4; ++i)
#pragma unroll
    for (int j = 0; j < 4; ++j) l[i][j] = 0.f;

  for (int c = 0; c < 8; ++c) {
    const int cb = c * 256 + w * 64;   // this wave's 64-col slice
#pragma unroll
    for (int ct = 0; ct < 4; ++ct) {
      const int kcol = cb + ct * 16 + col;
      bf16x8 kb0 = load8_bf16(Kb + kcol * DH + quad * 8);
      bf16x8 kb1 = load8_bf16(Kb + kcol * DH + 32 + quad * 8);
#pragma unroll
      for (int rt = 0; rt < 4; ++rt) {
        f32x4 acc = {0.f, 0.f, 0.f, 0.f};
        acc = __builtin_amdgcn_mfma_f32_16x16x32_bf16(qa[rt][0], kb0, acc, 0, 0, 0);
        acc = __builtin_amdgcn_mfma_f32_16x16x32_bf16(qa[rt][1], kb1, acc, 0, 0, 0);
#pragma unroll
        for (int r = 0; r < 4; ++r) l[rt][r] += __expf(acc[r] * 0.125f);
      }
    }
  }

  // butterfly-sum over the 16 lanes of each quad (cols within the wave slice)
#pragma unroll
  for (int m = 1; m <= 8; m <<= 1)
#pragma unroll
    for (int rt = 0; rt < 4; ++rt)
#pragma unroll
      for (int r = 0; r < 4; ++r) l[rt][r] += __shfl_xor(l[rt][r], m, 64);

  if (col == 0) {
#pragma unroll
    for (int rt = 0; rt < 4; ++rt)
#pragma unroll
      for (int r = 0; r < 4; ++r) rs[rt * 16 + quad * 4 + r][w] = l[rt][r];
  }
  __syncthreads();

  float invl[4][4];
#pragma unroll
  for (int rt = 0; rt < 4; ++rt)
#pragma unroll
    for (int r = 0; r < 4; ++r) {
      const float4 t = *(const float4*)&rs[rt * 16 + quad * 4 + r][0];
      invl[rt][r] = 1.0f / (t.x + t.y + t.z + t.w);
    }

  // ================= phase 2: accumulate PV, write attn coalesced =================
  f32x4 oacc[4][4];  // [row-tile][dim-tile]
#pragma unroll
  for (int i = 0; i < 4; ++i)
#pragma unroll
    for (int j = 0; j < 4; ++j) oacc[i][j] = (f32x4){0.f, 0.f, 0.f, 0.f};

  for (int c = 0; c < 8; ++c) {
    const int cb = c * 256 + w * 64;
#pragma unroll
    for (int ct = 0; ct < 4; ++ct) {
      const int kcol = cb + ct * 16 + col;
      bf16x8 kb0 = load8_bf16(Kb + kcol * DH + quad * 8);
      bf16x8 kb1 = load8_bf16(Kb + kcol * DH + 32 + quad * 8);
#pragma unroll
      for (int rt = 0; rt < 4; ++rt) {
        f32x4 acc = {0.f, 0.f, 0.f, 0.f};
        acc = __builtin_amdgcn_mfma_f32_16x16x32_bf16(qa[rt][0], kb0, acc, 0, 0, 0);
        acc = __builtin_amdgcn_mfma_f32_16x16x32_bf16(qa[rt][1], kb1, acc, 0, 0, 0);
#pragma unroll
        for (int r = 0; r < 4; ++r) {
          const float p = __expf(acc[r] * 0.125f) * invl[rt][r];
          const int row = rt * 16 + quad * 4 + r;
          ptile[w][row][ct * 16 + col] = f2bf(p);   // C-layout scatter (wave-private)
        }
      }
    }
    // PV: oacc += P[64 x 64] * V[64 x 64]  (wave-synchronous LDS round-trip, no barrier)
#pragma unroll
    for (int ks = 0; ks < 2; ++ks) {
      bf16x8 pa[4];
#pragma unroll
      for (int mt = 0; mt < 4; ++mt)
        pa[mt] = *(const bf16x8*)&ptile[w][mt * 16 + col][ks * 32 + quad * 8];
#pragma unroll
      for (int nt = 0; nt < 4; ++nt) {
        bf16x8 vb;
#pragma unroll
        for (int j = 0; j < 8; ++j)
          vb[j] = f2bf(Vb[(cb + ks * 32 + quad * 8 + j) * DH + nt * 16 + col]);
#pragma unroll
        for (int mt = 0; mt < 4; ++mt)
          oacc[mt][nt] = __builtin_amdgcn_mfma_f32_16x16x32_bf16(pa[mt], vb, oacc[mt][nt], 0, 0, 0);
      }
    }
    // Coalesced attn store from ptile (bf16 -> f32). Per instruction: 8 lanes
    // cover one row's 64 cols as 256 B contiguous; 8 rows/instr -> full 128 B
    // lines, no write-allocate RMW fetch. Replaces 64 scalar stores/lane with
    // 16 dwordx4 stores/lane per c-iter.
#pragma unroll
    for (int i = 0; i < 8; ++i) {
      const int row = i * 8 + (lane >> 3);
      const int cc  = (lane & 7) * 8;
      const bf16x8 t = *(const bf16x8*)&ptile[w][row][cc];
      float4 lo, hi;
      lo.x = bf2f(t[0]); lo.y = bf2f(t[1]); lo.z = bf2f(t[2]); lo.w = bf2f(t[3]);
      hi.x = bf2f(t[4]); hi.y = bf2f(t[5]); hi.z = bf2f(t[6]); hi.w = bf2f(t[7]);
      float* gp = Ab + (size_t)(qbase + row) * S + cb + cc;
      ((float4*)gp)[0] = lo;
      ((float4*)gp)[1] = hi;
    }
  }

  // ============ cross-wave reduction of output, then coalesced store ============
  __syncthreads();   // obuf aliases ptile[0..1]; waves 0/1 must be done reading
  for (int wv = 0; wv < 4; ++wv) {
    if (w == wv) {
#pragma unroll
      for (int mt = 0; mt < 4; ++mt)
#pragma unroll
        for (int nt = 0; nt < 4; ++nt)
#pragma unroll
          for (int r = 0; r < 4; ++r) {
            const int row = mt * 16 + quad * 4 + r;
            if (wv == 0) obuf[row][nt * 16 + col]  = oacc[mt][nt][r];
            else         obuf[row][nt * 16 + col] += oacc[mt][nt][r];
          }
    }
    __syncthreads();
  }

  {
    const int row = tid >> 2;
    const int seg = (tid & 3) * 16;
    float* gp = Out + ((size_t)b * S + qbase + row) * DH + seg;
#pragma unroll
    for (int j = 0; j < 4; ++j) {
      const float4 vv = *(const float4*)&obuf[row][seg + j * 4];
      ((float4*)gp)[j] = vv;
    }
  }
}

extern "C" void kernel_launch(void* const* d_in, const int* in_sizes, int n_in,
                              void* d_out, int out_size, void* d_ws, size_t ws_size,
                              hipStream_t stream) {
  const float* q = (const float*)d_in[0];
  const float* k = (const float*)d_in[1];
  const float* v = (const float*)d_in[2];
  float* outp = (float*)d_out;                                  // [32,2048,64]
  float* attn = (float*)d_out + (size_t)NB * S * DH;            // [32,2048,2048]
  attn_kernel<<<dim3(NB * (S / 64)), dim3(256), 0, stream>>>(q, k, v, outp, attn);
}